// Round 6
// baseline (3176.512 us; speedup 1.0000x reference)
//
#include <hip/hip_runtime.h>
#include <hip/hip_bf16.h>
#include <math.h>

#define B_ 512
#define S_ 256
#define D_ 256
#define NLOC 50000
#define KX 448      // D + TEMP
#define G4 1024
#define NEGV -1000000000.0f

typedef __attribute__((ext_vector_type(8))) short short8;
typedef __attribute__((ext_vector_type(4))) float f32x4;

__device__ __forceinline__ float sigmoidf_(float x){ return 1.0f/(1.0f+expf(-x)); }
__device__ __forceinline__ float geluf_(float x){ return 0.5f*x*(1.0f+erff(x*0.70710678118654752f)); }
__device__ __forceinline__ unsigned short f2bf_(float x){
  __hip_bfloat16 h = __float2bfloat16(x);
  return *(unsigned short*)&h;
}
__device__ __forceinline__ float bf2f_(unsigned short u){
  __hip_bfloat16 h = *(__hip_bfloat16*)&u;
  return __bfloat162float(h);
}
// fast sigmoid: ~2e-7 rel, no cancellation issues
__device__ __forceinline__ float fsig_(float x){
  return __fdividef(1.0f, 1.0f + __expf(-x));
}
// cancellation-free fast tanh: odd poly for |x|<0.25, exp form otherwise (~3e-7 rel)
__device__ __forceinline__ float ftanh2_(float x){
  float ax = fabsf(x);
  float x2 = x*x;
  float tp = x*(1.0f + x2*(-0.3333333333f + x2*(0.1333333333f + x2*(-0.05396825397f))));
  float e  = __expf(2.0f*fminf(ax, 15.0f));
  float te = 1.0f - __fdividef(2.0f, e + 1.0f);
  te = copysignf(te, x);
  return ax < 0.25f ? tp : te;
}
__device__ __forceinline__ void gld_lds16_(const unsigned short* gsrc, unsigned short* ldst){
  __builtin_amdgcn_global_load_lds((const __attribute__((address_space(1))) void*)gsrc,
                                   (__attribute__((address_space(3))) void*)ldst, 16, 0, 0);
}

// ---- init flag ----
__global__ void k_init(int* flag){
  if (blockIdx.x==0 && threadIdx.x==0) *flag = 0;
}

// ---- detect mask layout: any nonzero odd byte in first B*S bytes => uint8 ----
__global__ void k_detect(const unsigned char* m, int* flag){
  int i = blockIdx.x*256 + threadIdx.x;
  if ((i & 1) && i < B_*S_ && m[i]) atomicOr(flag, 1);
}

// ---- seq_lens[b] = count(mask row) - 1 ----
__global__ void k_seqlen(const void* mp, const int* flag, int* slens){
  int b = blockIdx.x*256 + threadIdx.x;
  if (b >= B_) return;
  int cnt = 0;
  if (*flag){
    const unsigned char* m = (const unsigned char*)mp;
    for (int s=0;s<S_;s++) cnt += (m[b*S_+s] != 0);
  } else {
    const int* m = (const int*)mp;
    for (int s=0;s<S_;s++) cnt += (m[b*S_+s] != 0);
  }
  slens[b] = cnt - 1;
}

// ---- convert W_ih to bf16; btot = b_ih + b_hh ----
__global__ void k_buildw(const float* wih, const float* bih, const float* bhh,
                         unsigned short* Wihbf, float* btot){
  int i = blockIdx.x*256 + threadIdx.x;
  if (i < G4*KX) Wihbf[i] = f2bf_(wih[i]);
  if (i < G4) btot[i] = bih[i] + bhh[i];
}

// ---- repack W_hh to per-(wave,kt,frag,lane) linear bf16 layout ----
// Whw[((w*8+kt)*8+f)*512 + lane*8 + e] = Whh[q*256 + w*32 + nt*16 + l16][kt*32 + quad*8 + e]
// with f = q*2+nt, lane = quad*16+l16. 512 KB total; per-wave frag c = kt*8+f.
__global__ void k_packw(const float* __restrict__ whh, unsigned short* __restrict__ Whw){
  int idx = blockIdx.x*256 + threadIdx.x;   // 0..32767
  if (idx >= 32768) return;
  int lane = idx & 63, f = (idx>>6)&7, kt = (idx>>9)&7, w = idx>>12;
  int q = f>>1, nt = f&1, l16 = lane&15, quad = lane>>4;
  int row = q*256 + w*32 + nt*16 + l16;
  int col = kt*32 + quad*8;
  const float* s = whh + (size_t)row*256 + col;
  short8 pk;
  #pragma unroll
  for (int e=0;e<8;e++) pk[e] = f2bf_(s[e]);
  *(short8*)(Whw + (size_t)idx*8) = pk;
}

// ---- Gx = X @ W_ih^T + btot, bf16 MFMA; output TIME-MAJOR: Gx[(t*B + b)*G4 + col] ----
__global__ __launch_bounds__(256) void k_gx(
    const int* __restrict__ loc, const int* __restrict__ usr,
    const int* __restrict__ wdy, const int* __restrict__ sm,
    const float* __restrict__ loct, const float* __restrict__ usert,
    const float* __restrict__ hourt, const float* __restrict__ wdt,
    const unsigned short* __restrict__ Wihbf, const float* __restrict__ btot,
    unsigned short* __restrict__ Gx){
  __shared__ unsigned short As[128][40];
  int tid = threadIdx.x;
  int n0 = blockIdx.x*128, m0 = blockIdx.y*128;
  int w = tid>>6, lane = tid&63;
  int quad = lane>>4, l16 = lane&15;
  int mw = (w>>1)*64, nw = (w&1)*64;
  f32x4 acc[4][4] = {};
  int r0 = tid>>2, seg = tid&3;
  for (int kt=0; kt<14; kt++){
    int k0 = kt*32;
    int kc = k0 + seg*8;
    #pragma unroll
    for (int rr=0; rr<2; rr++){
      int r = r0 + rr*64;
      int row = m0 + r;
      const float* src;
      if (kc < 256)      src = loct  + (size_t)loc[row]*256 + kc;
      else if (kc < 320) src = usert + (size_t)usr[row]*64 + (kc-256);
      else if (kc < 384) { int s = sm[row]; int hh = s/60; if (hh>24) hh=24; if (hh<0) hh=0;
                           src = hourt + (size_t)hh*64 + (kc-320); }
      else               src = wdt   + (size_t)wdy[row]*64 + (kc-384);
      float4 v0 = *(const float4*)(src);
      float4 v1 = *(const float4*)(src+4);
      short8 pk;
      pk[0]=f2bf_(v0.x); pk[1]=f2bf_(v0.y); pk[2]=f2bf_(v0.z); pk[3]=f2bf_(v0.w);
      pk[4]=f2bf_(v1.x); pk[5]=f2bf_(v1.y); pk[6]=f2bf_(v1.z); pk[7]=f2bf_(v1.w);
      *(short8*)&As[r][seg*8] = pk;
    }
    __syncthreads();
    short8 bfrag[4], afrag[4];
    #pragma unroll
    for (int nt=0; nt<4; nt++)
      bfrag[nt] = *(const short8*)(Wihbf + (size_t)(n0+nw+nt*16+l16)*KX + k0 + quad*8);
    #pragma unroll
    for (int mt=0; mt<4; mt++)
      afrag[mt] = *(const short8*)&As[mw+mt*16+l16][quad*8];
    #pragma unroll
    for (int mt=0; mt<4; mt++)
      #pragma unroll
      for (int nt=0; nt<4; nt++)
        acc[mt][nt] = __builtin_amdgcn_mfma_f32_16x16x32_bf16(afrag[mt], bfrag[nt], acc[mt][nt], 0, 0, 0);
    __syncthreads();
  }
  #pragma unroll
  for (int nt=0; nt<4; nt++){
    int col = n0 + nw + nt*16 + l16;
    float bv = btot[col];
    #pragma unroll
    for (int mt=0; mt<4; mt++){
      #pragma unroll
      for (int i=0; i<4; i++){
        int row = m0 + mw + mt*16 + quad*4 + i;   // row = b*S + t
        int bb = row >> 8, tt = row & 255;
        Gx[((size_t)tt*B_ + bb)*G4 + col] = f2bf_(acc[mt][nt][i] + bv);
      }
    }
  }
}

// ---- persistent LSTM: one kernel, all 256 steps. 32 blocks x 512 thr (8 waves). ----
// Per-wave Whh slice = 64 frags x 1KB (repacked, frag c = kt*8+f):
//   c0..3 -> LDS static (32KB, loaded once); c4..63 (60 frags) streamed through an
//   8-slot/wave LDS ring in CHUNKS OF 4: per chunk {vmcnt(4) -> 4x ds_read_b128 ->
//   lgkmcnt(0) (slot reuse provably safe) -> issue chunk k+2 fills -> 4 MFMAs}.
//   2 chunks (8KB/wave, 64KB/CU) in flight -> L2 port BW-bound, waits amortized 4x.
// LDS total = 139264B (validated size) -> 1 block/CU, 2 waves/SIMD.
__global__ __launch_bounds__(512, 2) void k_lstm(
    const unsigned short* __restrict__ Gx,      // [S][B][1024] time-major
    const unsigned short* __restrict__ Whw,     // repacked weights
    float* __restrict__ ctx, const int* __restrict__ slens){
  __shared__ unsigned short h_s[16][256];       // 8 KB, XOR-swizzled 16B chunks
  __shared__ unsigned short gx_s[16*1024];      // 32 KB, staged same-step
  __shared__ unsigned short whhl[8][4][512];    // 32 KB static: frags c0..3 per wave
  __shared__ unsigned short whr[8][8][512];     // 64 KB ring: 8 slots per wave
  int tid = threadIdx.x;
  int w = tid >> 6, lane = tid & 63;
  int quad = lane >> 4, l16 = lane & 15;
  int b0 = blockIdx.x * 16;
  int dw = w * 32;

  for (int i = tid; i < 16*256; i += 512) ((unsigned short*)h_s)[i] = 0;

  // static LDS weight cache: frags c0..3 (kt0 f0..3), linear gld_lds
  #pragma unroll
  for (int c=0; c<4; c++)
    gld_lds16_(Whw + ((size_t)(w*64 + c))*512 + lane*8, &whhl[w][c][0]);

  float cst[2][4] = {{0.f,0.f,0.f,0.f},{0.f,0.f,0.f,0.f}};
  int slq[4];
  #pragma unroll
  for (int i=0;i<4;i++) slq[i] = slens[b0 + quad*4 + i];

  asm volatile("s_waitcnt vmcnt(0) lgkmcnt(0)" ::: "memory");
  __syncthreads();

  const unsigned short* sb = Whw + ((size_t)(w*64 + 4))*512 + lane*8;  // stream base (frag c=4)

  for (int t=0; t<S_; t++){
    // 1. stage this step's Gx slice (issued first; in-order vmcnt completion
    //    means gx_s is complete once chunk 0's wait clears)
    {
      const unsigned short* src = Gx + ((size_t)t*B_ + b0)*G4 + w*2048 + lane*8;
      #pragma unroll
      for (int j=0;j<4;j++) gld_lds16_(src + j*512, &gx_s[w*2048 + j*512]);
    }
    // 2. ring prologue: fills for chunks 0 (slots 0-3) and 1 (slots 4-7)
    #pragma unroll
    for (int k=0;k<2;k++)
      #pragma unroll
      for (int j=0;j<4;j++)
        gld_lds16_(sb + (size_t)(4*k+j)*512, &whr[w][k*4+j][0]);
    __builtin_amdgcn_sched_barrier(0);

    // 3. a-frags + static MFMAs (c0..3) — covers initial fill latency
    short8 af[8];
    #pragma unroll
    for (int kt=0;kt<8;kt++)
      af[kt] = *(const short8*)((const char*)h_s + l16*512 + ((((kt<<2)|quad) ^ (l16&7))<<4));
    f32x4 acc[4][2] = {};
    #pragma unroll
    for (int f=0;f<4;f++)
      acc[f>>1][f&1] = __builtin_amdgcn_mfma_f32_16x16x32_bf16(
          af[0], *(const short8*)&whhl[w][f][lane*8], acc[f>>1][f&1], 0, 0, 0);
    __builtin_amdgcn_sched_barrier(0);

    // 4. chunked stream: 15 chunks x 4 frags (c = 4+4k+j), 8-slot ring
    #pragma unroll
    for (int k=0;k<15;k++){
      if (k < 14) asm volatile("s_waitcnt vmcnt(4)" ::: "memory");  // chunk k landed
      else        asm volatile("s_waitcnt vmcnt(0)" ::: "memory");
      __builtin_amdgcn_sched_barrier(0);
      short8 bb[4];
      #pragma unroll
      for (int j=0;j<4;j++) bb[j] = *(const short8*)&whr[w][(k&1)*4+j][lane*8];
      asm volatile("s_waitcnt lgkmcnt(0)" ::: "memory");   // reads done -> slots reusable
      __builtin_amdgcn_sched_barrier(0);
      if (k+2 < 15){
        #pragma unroll
        for (int j=0;j<4;j++)
          gld_lds16_(sb + (size_t)(4*(k+2)+j)*512, &whr[w][(k&1)*4+j][0]);
      }
      __builtin_amdgcn_sched_barrier(0);
      #pragma unroll
      for (int j=0;j<4;j++){
        int c = 4 + 4*k + j;
        acc[(c&7)>>1][c&1] = __builtin_amdgcn_mfma_f32_16x16x32_bf16(
            af[c>>3], bb[j], acc[(c&7)>>1][c&1], 0, 0, 0);
      }
    }

    // pre-epilogue: all vm (gx included) and lgkm complete
    asm volatile("s_waitcnt vmcnt(0) lgkmcnt(0)" ::: "memory");
    __builtin_amdgcn_sched_barrier(0);
    __builtin_amdgcn_s_barrier();

    // epilogue: gates + cell update (gx read as u32 pairs)
    const unsigned int* gxw = (const unsigned int*)&gx_s[0];
    int half = l16 & 1;
    #pragma unroll
    for (int nt=0;nt<2;nt++){
      int d = dw + nt*16 + l16;
      int dbase2 = (dw + nt*16) >> 1;
      int chunkx = d >> 3;
      #pragma unroll
      for (int i=0;i<4;i++){
        int r = quad*4 + i;
        int base = r*512 + dbase2 + (l16>>1);
        unsigned int u0 = gxw[base];
        unsigned int u1 = gxw[base + 128];
        unsigned int u2 = gxw[base + 256];
        unsigned int u3 = gxw[base + 384];
        unsigned short s0 = half ? (unsigned short)(u0>>16) : (unsigned short)(u0&0xffff);
        unsigned short s1 = half ? (unsigned short)(u1>>16) : (unsigned short)(u1&0xffff);
        unsigned short s2 = half ? (unsigned short)(u2>>16) : (unsigned short)(u2&0xffff);
        unsigned short s3 = half ? (unsigned short)(u3>>16) : (unsigned short)(u3&0xffff);
        float gi = acc[0][nt][i] + bf2f_(s0);
        float gf = acc[1][nt][i] + bf2f_(s1);
        float gg = acc[2][nt][i] + bf2f_(s2);
        float go = acc[3][nt][i] + bf2f_(s3);
        float cn = fsig_(gf)*cst[nt][i] + fsig_(gi)*ftanh2_(gg);
        float hn = fsig_(go)*ftanh2_(cn);
        cst[nt][i] = cn;
        *(unsigned short*)((char*)h_s + r*512 + ((chunkx ^ (r&7))<<4) + (d&7)*2) = f2bf_(hn);
        if (t == slq[i]) ctx[(size_t)(b0 + r)*D_ + d] = hn;
      }
    }

    // end barrier: h_s writes visible before next iteration's reads
    asm volatile("s_waitcnt lgkmcnt(0)" ::: "memory");
    __builtin_amdgcn_sched_barrier(0);
    __builtin_amdgcn_s_barrier();
  }
}

// ---- newhid = gelu(ctx @ np_W1^T + np_b1); mix = sigmoid(ctx . mx_W + mx_b)*0.9+0.05 ----
__global__ void k_post1(const float* __restrict__ ctx, const float* __restrict__ W1,
                        const float* __restrict__ b1, const float* __restrict__ mxW,
                        const float* __restrict__ mxb, float* newhid, float* mixv){
  __shared__ float cs[256];
  __shared__ float red[256];
  int b = blockIdx.x, tid = threadIdx.x;
  cs[tid] = ctx[(size_t)b*D_ + tid];
  __syncthreads();
  float a = b1[tid];
  const float* wr = W1 + (size_t)tid*D_;
  for (int k=0; k<D_; k++) a += cs[k]*wr[k];
  newhid[(size_t)b*D_ + tid] = geluf_(a);
  red[tid] = cs[tid]*mxW[tid];
  __syncthreads();
  for (int s=128; s>0; s>>=1){ if (tid<s) red[tid]+=red[tid+s]; __syncthreads(); }
  if (tid==0) mixv[b] = sigmoidf_(red[0]+mxb[0])*0.9f + 0.05f;
}

// ---- recent-location scores + dedup/keep ----
__global__ void k_recent(const int* __restrict__ loc, const int* __restrict__ sm,
                         const int* __restrict__ slens, const float* __restrict__ loct,
                         const float* __restrict__ W1, const float* __restrict__ b1,
                         const float* __restrict__ W2, const float* __restrict__ b2,
                         float* scores, int* rlocs, int* keep){
  __shared__ int rl[5], vs[5];
  __shared__ float td[5];
  __shared__ float red[128];
  int b = blockIdx.x, tid = threadIdx.x;
  int sl = slens[b];
  if (tid < 5){
    int idx = sl - tid;
    int v = idx >= 0;
    int ic = v ? idx : 0;
    rl[tid] = loc[b*S_ + ic];
    vs[tid] = v;
    int cur = sm[b*S_ + sl];
    td[tid] = (float)(cur - sm[b*S_ + ic]) * (1.0f/1440.0f);
  }
  __syncthreads();
  for (int j=0; j<5; j++){
    const float* lrow = loct + (size_t)rl[j]*D_;
    const float* wr = W1 + (size_t)tid*258;
    float a = b1[tid];
    for (int k=0; k<D_; k++) a += lrow[k]*wr[k];
    a += td[j]*wr[256] + (float)j*wr[257];
    red[tid] = geluf_(a)*W2[tid];
    __syncthreads();
    for (int s=64; s>0; s>>=1){ if (tid<s) red[tid]+=red[tid+s]; __syncthreads(); }
    if (tid==0) scores[b*5+j] = red[0] + b2[0];
    __syncthreads();
  }
  if (tid==0){
    for (int j=0; j<5; j++){
      int dup = 0;
      for (int k=0; k<j; k++) dup |= (rl[j]==rl[k]) && vs[k];
      keep[b*5+j] = vs[j] && !dup;
      rlocs[b*5+j] = rl[j];
    }
  }
}

// ---- big fused head: out[b,l] = mix*NEG + (1-mix)*(newhid[b].np_W2[l] + np_b2[l]) ----
__global__ __launch_bounds__(256) void k_final(const float* __restrict__ newhid,
    const float* __restrict__ W2, const float* __restrict__ b2,
    const float* __restrict__ mixv, float* __restrict__ out){
  __shared__ float Hs[16][260];   // pad 260: quads hit distinct banks
  __shared__ float Wl[64][65];
  int tid = threadIdx.x;
  int l0 = blockIdx.x*64, b0 = blockIdx.y*16;
  int ll = tid & 63, bq = tid >> 6;
  #pragma unroll
  for (int r=0; r<16; r++) Hs[r][tid] = newhid[(size_t)(b0+r)*D_ + tid];
  float acc[4] = {0.f,0.f,0.f,0.f};
  for (int kt=0; kt<4; kt++){
    int k0 = kt*64;
    __syncthreads();
    #pragma unroll
    for (int r=0; r<4; r++){
      int row = 4*r + bq;
      int l = l0 + row;
      Wl[row][ll] = (l < NLOC) ? W2[(size_t)l*D_ + k0 + ll] : 0.f;
    }
    __syncthreads();
    #pragma unroll
    for (int kk=0; kk<64; kk++){
      float wv = Wl[ll][kk];
      #pragma unroll
      for (int bi=0; bi<4; bi++) acc[bi] += wv * Hs[bq*4+bi][k0+kk];
    }
  }
  int l = l0 + ll;
  if (l < NLOC){
    float bias = b2[l];
    #pragma unroll
    for (int bi=0; bi<4; bi++){
      int b = b0 + bq*4 + bi;
      float mx = mixv[b];
      out[(size_t)b*NLOC + l] = mx*NEGV + (1.0f-mx)*(acc[bi] + bias);
    }
  }
}

// ---- overwrite kept recent locations ----
__global__ void k_scatter(const float* __restrict__ newhid, const float* __restrict__ W2,
                          const float* __restrict__ b2, const float* __restrict__ mixv,
                          const float* __restrict__ scores, const int* __restrict__ rlocs,
                          const int* __restrict__ keep, float* out){
  int b = blockIdx.x, lane = threadIdx.x;
  float mx = mixv[b];
  for (int j=0; j<5; j++){
    if (!keep[b*5+j]) continue;
    int rl = rlocs[b*5+j];
    const float* wr = W2 + (size_t)rl*D_;
    const float* hr = newhid + (size_t)b*D_;
    float a = 0.f;
    #pragma unroll
    for (int q=0; q<4; q++){ int k = lane + 64*q; a += hr[k]*wr[k]; }
    #pragma unroll
    for (int off=32; off>0; off>>=1) a += __shfl_xor(a, off, 64);
    if (lane==0)
      out[(size_t)b*NLOC + rl] = mx*scores[b*5+j] + (1.0f-mx)*(a + b2[rl]);
  }
}

extern "C" void kernel_launch(void* const* d_in, const int* in_sizes, int n_in,
                              void* d_out, int out_size, void* d_ws, size_t ws_size,
                              hipStream_t stream){
  const int* locations   = (const int*)d_in[0];
  const int* users       = (const int*)d_in[1];
  const int* weekdays    = (const int*)d_in[2];
  const int* start_mins  = (const int*)d_in[3];
  const void* mask       = d_in[4];
  const float* loc_table = (const float*)d_in[5];
  const float* user_table= (const float*)d_in[6];
  const float* hour_table= (const float*)d_in[7];
  const float* wd_table  = (const float*)d_in[8];
  const float* W_ih      = (const float*)d_in[9];
  const float* W_hh      = (const float*)d_in[10];
  const float* b_ih      = (const float*)d_in[11];
  const float* b_hh      = (const float*)d_in[12];
  const float* sc_W1     = (const float*)d_in[13];
  const float* sc_b1     = (const float*)d_in[14];
  const float* sc_W2     = (const float*)d_in[15];
  const float* sc_b2     = (const float*)d_in[16];
  const float* np_W1     = (const float*)d_in[17];
  const float* np_b1     = (const float*)d_in[18];
  const float* np_W2     = (const float*)d_in[19];
  const float* np_b2     = (const float*)d_in[20];
  const float* mx_W      = (const float*)d_in[21];
  const float* mx_b      = (const float*)d_in[22];
  float* out = (float*)d_out;

  char* w = (char*)d_ws;
  size_t o = 0;
  auto alloc = [&](size_t bytes)->void*{ void* p = w + o; o += (bytes + 255) & ~(size_t)255; return p; };
  unsigned short* Gx    = (unsigned short*)alloc((size_t)B_*S_*G4*sizeof(short)); // 268 MB bf16, time-major
  unsigned short* Wihbf = (unsigned short*)alloc((size_t)G4*KX*sizeof(short));
  unsigned short* Whw   = (unsigned short*)alloc((size_t)G4*D_*sizeof(short));    // repacked Whh
  float* btot   = (float*)alloc((size_t)G4*sizeof(float));
  float* ctx    = (float*)alloc((size_t)B_*D_*sizeof(float));
  float* newhid = (float*)alloc((size_t)B_*D_*sizeof(float));
  float* mixv   = (float*)alloc((size_t)B_*sizeof(float));
  float* scores = (float*)alloc((size_t)B_*5*sizeof(float));
  int*   slens  = (int*)alloc((size_t)B_*sizeof(int));
  int*   rlocs  = (int*)alloc((size_t)B_*5*sizeof(int));
  int*   keep   = (int*)alloc((size_t)B_*5*sizeof(int));
  int*   flag   = (int*)alloc(sizeof(int));

  k_init<<<1, 64, 0, stream>>>(flag);
  k_detect<<<512, 256, 0, stream>>>((const unsigned char*)mask, flag);
  k_seqlen<<<2, 256, 0, stream>>>(mask, flag, slens);
  k_buildw<<<1792, 256, 0, stream>>>(W_ih, b_ih, b_hh, Wihbf, btot);
  k_packw<<<128, 256, 0, stream>>>(W_hh, Whw);
  k_gx<<<dim3(8,1024), 256, 0, stream>>>(locations, users, weekdays, start_mins,
                                         loc_table, user_table, hour_table, wd_table,
                                         Wihbf, btot, Gx);
  k_lstm<<<32, 512, 0, stream>>>(Gx, Whw, ctx, slens);
  k_post1<<<512, 256, 0, stream>>>(ctx, np_W1, np_b1, mx_W, mx_b, newhid, mixv);
  k_recent<<<512, 128, 0, stream>>>(locations, start_mins, slens, loc_table,
                                    sc_W1, sc_b1, sc_W2, sc_b2, scores, rlocs, keep);
  k_final<<<dim3(782,32), 256, 0, stream>>>(newhid, np_W2, np_b2, mixv, out);
  k_scatter<<<512, 64, 0, stream>>>(newhid, np_W2, np_b2, mixv, scores, rlocs, keep, out);
}

// Round 9
// 2982.363 us; speedup vs baseline: 1.0651x; 1.0651x over previous
//
#include <hip/hip_runtime.h>
#include <hip/hip_bf16.h>
#include <math.h>

#define B_ 512
#define S_ 256
#define D_ 256
#define NLOC 50000
#define KX 448      // D + TEMP
#define G4 1024
#define NEGV -1000000000.0f

typedef __attribute__((ext_vector_type(8))) short short8;
typedef __attribute__((ext_vector_type(4))) float f32x4;

__device__ __forceinline__ float sigmoidf_(float x){ return 1.0f/(1.0f+expf(-x)); }
__device__ __forceinline__ float geluf_(float x){ return 0.5f*x*(1.0f+erff(x*0.70710678118654752f)); }
__device__ __forceinline__ unsigned short f2bf_(float x){
  __hip_bfloat16 h = __float2bfloat16(x);
  return *(unsigned short*)&h;
}
__device__ __forceinline__ float bf2f_(unsigned short u){
  __hip_bfloat16 h = *(__hip_bfloat16*)&u;
  return __bfloat162float(h);
}
// fast sigmoid: ~2e-7 rel
__device__ __forceinline__ float fsig_(float x){
  return __fdividef(1.0f, 1.0f + __expf(-x));
}
// cancellation-free fast tanh
__device__ __forceinline__ float ftanh2_(float x){
  float ax = fabsf(x);
  float x2 = x*x;
  float tp = x*(1.0f + x2*(-0.3333333333f + x2*(0.1333333333f + x2*(-0.05396825397f))));
  float e  = __expf(2.0f*fminf(ax, 15.0f));
  float te = 1.0f - __fdividef(2.0f, e + 1.0f);
  te = copysignf(te, x);
  return ax < 0.25f ? tp : te;
}
__device__ __forceinline__ void gld_lds16_(const void* gsrc, void* ldst){
  __builtin_amdgcn_global_load_lds((const __attribute__((address_space(1))) void*)gsrc,
                                   (__attribute__((address_space(3))) void*)ldst, 16, 0, 0);
}

// ---- init flag ----
__global__ void k_init(int* flag){
  if (blockIdx.x==0 && threadIdx.x==0) *flag = 0;
}

// ---- detect mask layout ----
__global__ void k_detect(const unsigned char* m, int* flag){
  int i = blockIdx.x*256 + threadIdx.x;
  if ((i & 1) && i < B_*S_ && m[i]) atomicOr(flag, 1);
}

// ---- seq_lens[b] = count(mask row) - 1 ----
__global__ void k_seqlen(const void* mp, const int* flag, int* slens){
  int b = blockIdx.x*256 + threadIdx.x;
  if (b >= B_) return;
  int cnt = 0;
  if (*flag){
    const unsigned char* m = (const unsigned char*)mp;
    for (int s=0;s<S_;s++) cnt += (m[b*S_+s] != 0);
  } else {
    const int* m = (const int*)mp;
    for (int s=0;s<S_;s++) cnt += (m[b*S_+s] != 0);
  }
  slens[b] = cnt - 1;
}

// ---- convert W_ih to bf16; btot = b_ih + b_hh ----
__global__ void k_buildw(const float* wih, const float* bih, const float* bhh,
                         unsigned short* Wihbf, float* btot){
  int i = blockIdx.x*256 + threadIdx.x;
  if (i < G4*KX) Wihbf[i] = f2bf_(wih[i]);
  if (i < G4) btot[i] = bih[i] + bhh[i];
}

// ---- repack W_hh to per-(wave,kt,frag,lane) linear FP8 (e4m3 OCP) layout ----
// Ww8[((w*8+kt)*8+f)*512 + lane*8 + e] = fp8(Whh[q*256+w*32+nt*16+l16][kt*32+quad*8+e])
// f = q*2+nt, lane = quad*16+l16. 256 KB total; per-wave frag c = kt*8+f (512 B each).
__global__ void k_packw(const float* __restrict__ whh, unsigned char* __restrict__ Ww8){
  int idx = blockIdx.x*256 + threadIdx.x;   // 0..32767
  if (idx >= 32768) return;
  int lane = idx & 63, f = (idx>>6)&7, kt = (idx>>9)&7, w = idx>>12;
  int q = f>>1, nt = f&1, l16 = lane&15, quad = lane>>4;
  int row = q*256 + w*32 + nt*16 + l16;
  int col = kt*32 + quad*8;
  const float* s = whh + (size_t)row*256 + col;
  unsigned lo, hi;
  lo = __builtin_amdgcn_cvt_pk_fp8_f32(s[0], s[1], 0, 0);
  lo = __builtin_amdgcn_cvt_pk_fp8_f32(s[2], s[3], lo, 1);
  hi = __builtin_amdgcn_cvt_pk_fp8_f32(s[4], s[5], 0, 0);
  hi = __builtin_amdgcn_cvt_pk_fp8_f32(s[6], s[7], hi, 1);
  uint2 v; v.x = lo; v.y = hi;
  *(uint2*)(Ww8 + (size_t)idx*8) = v;
}

// ---- Gx = X @ W_ih^T + btot, bf16 MFMA; TIME-MAJOR output ----
__global__ __launch_bounds__(256) void k_gx(
    const int* __restrict__ loc, const int* __restrict__ usr,
    const int* __restrict__ wdy, const int* __restrict__ sm,
    const float* __restrict__ loct, const float* __restrict__ usert,
    const float* __restrict__ hourt, const float* __restrict__ wdt,
    const unsigned short* __restrict__ Wihbf, const float* __restrict__ btot,
    unsigned short* __restrict__ Gx){
  __shared__ unsigned short As[128][40];
  int tid = threadIdx.x;
  int n0 = blockIdx.x*128, m0 = blockIdx.y*128;
  int w = tid>>6, lane = tid&63;
  int quad = lane>>4, l16 = lane&15;
  int mw = (w>>1)*64, nw = (w&1)*64;
  f32x4 acc[4][4] = {};
  int r0 = tid>>2, seg = tid&3;
  for (int kt=0; kt<14; kt++){
    int k0 = kt*32;
    int kc = k0 + seg*8;
    #pragma unroll
    for (int rr=0; rr<2; rr++){
      int r = r0 + rr*64;
      int row = m0 + r;
      const float* src;
      if (kc < 256)      src = loct  + (size_t)loc[row]*256 + kc;
      else if (kc < 320) src = usert + (size_t)usr[row]*64 + (kc-256);
      else if (kc < 384) { int s = sm[row]; int hh = s/60; if (hh>24) hh=24; if (hh<0) hh=0;
                           src = hourt + (size_t)hh*64 + (kc-320); }
      else               src = wdt   + (size_t)wdy[row]*64 + (kc-384);
      float4 v0 = *(const float4*)(src);
      float4 v1 = *(const float4*)(src+4);
      short8 pk;
      pk[0]=f2bf_(v0.x); pk[1]=f2bf_(v0.y); pk[2]=f2bf_(v0.z); pk[3]=f2bf_(v0.w);
      pk[4]=f2bf_(v1.x); pk[5]=f2bf_(v1.y); pk[6]=f2bf_(v1.z); pk[7]=f2bf_(v1.w);
      *(short8*)&As[r][seg*8] = pk;
    }
    __syncthreads();
    short8 bfrag[4], afrag[4];
    #pragma unroll
    for (int nt=0; nt<4; nt++)
      bfrag[nt] = *(const short8*)(Wihbf + (size_t)(n0+nw+nt*16+l16)*KX + k0 + quad*8);
    #pragma unroll
    for (int mt=0; mt<4; mt++)
      afrag[mt] = *(const short8*)&As[mw+mt*16+l16][quad*8];
    #pragma unroll
    for (int mt=0; mt<4; mt++)
      #pragma unroll
      for (int nt=0; nt<4; nt++)
        acc[mt][nt] = __builtin_amdgcn_mfma_f32_16x16x32_bf16(afrag[mt], bfrag[nt], acc[mt][nt], 0, 0, 0);
    __syncthreads();
  }
  #pragma unroll
  for (int nt=0; nt<4; nt++){
    int col = n0 + nw + nt*16 + l16;
    float bv = btot[col];
    #pragma unroll
    for (int mt=0; mt<4; mt++){
      #pragma unroll
      for (int i=0; i<4; i++){
        int row = m0 + mw + mt*16 + quad*4 + i;   // row = b*S + t
        int bb = row >> 8, tt = row & 255;
        Gx[((size_t)tt*B_ + bb)*G4 + col] = f2bf_(acc[mt][nt][i] + bv);
      }
    }
  }
}

#define CONSUME8(BATCH, CBASE) \
  _Pragma("unroll") \
  for (int j=0;j<8;j++){ int c = (CBASE)+j; \
    acc[(c&7)>>1][c&1] = __builtin_amdgcn_mfma_f32_16x16x32_fp8_fp8( \
        af[c>>3], BATCH[j], acc[(c&7)>>1][c&1], 0, 0, 0); }

// ---- persistent LSTM, FP8 weights+h. 32 blocks x 512 thr (8 waves). ----
// Per-wave Whh slice = 64 fp8 frags x 512B = 32KB: c0..23 LDS-static (96KB block,
// loaded once); c24..63 streamed L2->REGISTERS in five 8-frag x 16-reg batches
// (~150 live VGPRs: no allocator pressure -> no remat). Per-step bytes/CU:
// 160KB stream + 32KB gx vs 544KB before (the measured per-CU L2-path wall).
// LDS = 135168B < proven 139264. Gx stays bf16; epilogue unchanged.
__global__ __launch_bounds__(512, 2) void k_lstm(
    const unsigned short* __restrict__ Gx,      // [S][B][1024] time-major bf16
    const unsigned char* __restrict__ Ww8,      // repacked fp8 weights
    float* __restrict__ ctx, const int* __restrict__ slens){
  __shared__ unsigned char h_s[16*256];         // 4 KB fp8 h, XOR-swizzled 8B chunks
  __shared__ unsigned short gx_s[16*1024];      // 32 KB bf16
  __shared__ unsigned char whhs[8*12288];       // 96 KB static: frags c0..23 per wave
  int tid = threadIdx.x;
  int w = tid >> 6, lane = tid & 63;
  int quad = lane >> 4, l16 = lane & 15;
  int b0 = blockIdx.x * 16;
  int dw = w * 32;

  for (int i = tid; i < 16*256; i += 512) h_s[i] = 0;

  // static LDS weight fill: 12 KB/wave contiguous (frags c0..23)
  #pragma unroll
  for (int j=0;j<12;j++)
    gld_lds16_(Ww8 + (size_t)w*32768 + j*1024 + lane*16, &whhs[w*12288 + j*1024]);

  float cst[2][4] = {{0.f,0.f,0.f,0.f},{0.f,0.f,0.f,0.f}};
  int slq[4];
  #pragma unroll
  for (int i=0;i<4;i++) slq[i] = slens[b0 + quad*4 + i];

  asm volatile("s_waitcnt vmcnt(0) lgkmcnt(0)" ::: "memory");
  __syncthreads();

  for (int t=0; t<S_; t++){
    // laundered per-step base: SGPR-only (uniform kernel arg) -> legal "+s";
    // wave/lane offsets applied AFTER laundering (round-8 fix: w*32768 in the
    // laundered operand forced an illegal VGPR->SGPR copy)
    unsigned long long pb = (unsigned long long)Ww8;
    asm volatile("" : "+s"(pb));
    const unsigned char* sb = (const unsigned char*)pb + (size_t)w*32768 + lane*8;

    long long B1[8], B2[8], B3[8], B4[8], B5[8];
    #pragma unroll
    for (int j=0;j<8;j++) B1[j] = *(const long long*)(sb + (size_t)(24+j)*512);
    #pragma unroll
    for (int j=0;j<8;j++) B2[j] = *(const long long*)(sb + (size_t)(32+j)*512);
    __builtin_amdgcn_sched_barrier(0);

    // a-frags (fp8 h) + static MFMAs c0..23 (covers B1/B2 latency)
    long long af[8];
    #pragma unroll
    for (int kt=0;kt<8;kt++)
      af[kt] = *(const long long*)&h_s[l16*256 + ((((kt<<2)|quad) ^ (l16&7))<<3)];
    f32x4 acc[4][2] = {};
    #pragma unroll
    for (int c=0;c<24;c++){
      long long bfr = *(const long long*)&whhs[w*12288 + c*512 + lane*8];
      acc[(c&7)>>1][c&1] = __builtin_amdgcn_mfma_f32_16x16x32_fp8_fp8(
          af[c>>3], bfr, acc[(c&7)>>1][c&1], 0, 0, 0);
    }
    __builtin_amdgcn_sched_barrier(0);

    // issue B3 + this step's Gx staging (HBM latency hides under B1..B3 consume)
    #pragma unroll
    for (int j=0;j<8;j++) B3[j] = *(const long long*)(sb + (size_t)(40+j)*512);
    {
      const unsigned short* src = Gx + ((size_t)t*B_ + b0)*G4 + w*2048 + lane*8;
      #pragma unroll
      for (int j=0;j<4;j++) gld_lds16_(src + j*512, &gx_s[w*2048 + j*512]);
    }
    __builtin_amdgcn_sched_barrier(0);

    CONSUME8(B1, 24)
    #pragma unroll
    for (int j=0;j<8;j++) B4[j] = *(const long long*)(sb + (size_t)(48+j)*512);
    __builtin_amdgcn_sched_barrier(0);

    CONSUME8(B2, 32)
    #pragma unroll
    for (int j=0;j<8;j++) B5[j] = *(const long long*)(sb + (size_t)(56+j)*512);
    __builtin_amdgcn_sched_barrier(0);

    CONSUME8(B3, 40)
    CONSUME8(B4, 48)
    CONSUME8(B5, 56)

    // pre-epilogue: gx staged (vm), all LDS reads done (lgkm)
    asm volatile("s_waitcnt vmcnt(0) lgkmcnt(0)" ::: "memory");
    __builtin_amdgcn_sched_barrier(0);
    __builtin_amdgcn_s_barrier();

    // epilogue: gates + cell update (gx read as u32 pairs; c/ctx stay f32)
    const unsigned int* gxw = (const unsigned int*)&gx_s[0];
    int half = l16 & 1;
    #pragma unroll
    for (int nt=0;nt<2;nt++){
      int d = dw + nt*16 + l16;
      int dbase2 = (dw + nt*16) >> 1;
      #pragma unroll
      for (int i=0;i<4;i++){
        int r = quad*4 + i;
        int base = r*512 + dbase2 + (l16>>1);
        unsigned int u0 = gxw[base];
        unsigned int u1 = gxw[base + 128];
        unsigned int u2 = gxw[base + 256];
        unsigned int u3 = gxw[base + 384];
        unsigned short s0 = half ? (unsigned short)(u0>>16) : (unsigned short)(u0&0xffff);
        unsigned short s1 = half ? (unsigned short)(u1>>16) : (unsigned short)(u1&0xffff);
        unsigned short s2 = half ? (unsigned short)(u2>>16) : (unsigned short)(u2&0xffff);
        unsigned short s3 = half ? (unsigned short)(u3>>16) : (unsigned short)(u3&0xffff);
        float gi = acc[0][nt][i] + bf2f_(s0);
        float gf = acc[1][nt][i] + bf2f_(s1);
        float gg = acc[2][nt][i] + bf2f_(s2);
        float go = acc[3][nt][i] + bf2f_(s3);
        float cn = fsig_(gf)*cst[nt][i] + fsig_(gi)*ftanh2_(gg);
        float hn = fsig_(go)*ftanh2_(cn);
        cst[nt][i] = cn;
        int p8 = __builtin_amdgcn_cvt_pk_fp8_f32(hn, hn, 0, 0);
        h_s[r*256 + (((d>>3) ^ (r&7))<<3) + (d&7)] = (unsigned char)(p8 & 0xff);
        if (t == slq[i]) ctx[(size_t)(b0 + r)*D_ + d] = hn;
      }
    }

    // end barrier: h_s writes visible before next iteration's reads
    asm volatile("s_waitcnt lgkmcnt(0)" ::: "memory");
    __builtin_amdgcn_sched_barrier(0);
    __builtin_amdgcn_s_barrier();
  }
}

// ---- newhid = gelu(ctx @ np_W1^T + np_b1); mix ----
__global__ void k_post1(const float* __restrict__ ctx, const float* __restrict__ W1,
                        const float* __restrict__ b1, const float* __restrict__ mxW,
                        const float* __restrict__ mxb, float* newhid, float* mixv){
  __shared__ float cs[256];
  __shared__ float red[256];
  int b = blockIdx.x, tid = threadIdx.x;
  cs[tid] = ctx[(size_t)b*D_ + tid];
  __syncthreads();
  float a = b1[tid];
  const float* wr = W1 + (size_t)tid*D_;
  for (int k=0; k<D_; k++) a += cs[k]*wr[k];
  newhid[(size_t)b*D_ + tid] = geluf_(a);
  red[tid] = cs[tid]*mxW[tid];
  __syncthreads();
  for (int s=128; s>0; s>>=1){ if (tid<s) red[tid]+=red[tid+s]; __syncthreads(); }
  if (tid==0) mixv[b] = sigmoidf_(red[0]+mxb[0])*0.9f + 0.05f;
}

// ---- recent-location scores + dedup/keep ----
__global__ void k_recent(const int* __restrict__ loc, const int* __restrict__ sm,
                         const int* __restrict__ slens, const float* __restrict__ loct,
                         const float* __restrict__ W1, const float* __restrict__ b1,
                         const float* __restrict__ W2, const float* __restrict__ b2,
                         float* scores, int* rlocs, int* keep){
  __shared__ int rl[5], vs[5];
  __shared__ float td[5];
  __shared__ float red[128];
  int b = blockIdx.x, tid = threadIdx.x;
  int sl = slens[b];
  if (tid < 5){
    int idx = sl - tid;
    int v = idx >= 0;
    int ic = v ? idx : 0;
    rl[tid] = loc[b*S_ + ic];
    vs[tid] = v;
    int cur = sm[b*S_ + sl];
    td[tid] = (float)(cur - sm[b*S_ + ic]) * (1.0f/1440.0f);
  }
  __syncthreads();
  for (int j=0; j<5; j++){
    const float* lrow = loct + (size_t)rl[j]*D_;
    const float* wr = W1 + (size_t)tid*258;
    float a = b1[tid];
    for (int k=0; k<D_; k++) a += lrow[k]*wr[k];
    a += td[j]*wr[256] + (float)j*wr[257];
    red[tid] = geluf_(a)*W2[tid];
    __syncthreads();
    for (int s=64; s>0; s>>=1){ if (tid<s) red[tid]+=red[tid+s]; __syncthreads(); }
    if (tid==0) scores[b*5+j] = red[0] + b2[0];
    __syncthreads();
  }
  if (tid==0){
    for (int j=0; j<5; j++){
      int dup = 0;
      for (int k=0; k<j; k++) dup |= (rl[j]==rl[k]) && vs[k];
      keep[b*5+j] = vs[j] && !dup;
      rlocs[b*5+j] = rl[j];
    }
  }
}

// ---- big fused head ----
__global__ __launch_bounds__(256) void k_final(const float* __restrict__ newhid,
    const float* __restrict__ W2, const float* __restrict__ b2,
    const float* __restrict__ mixv, float* __restrict__ out){
  __shared__ float Hs[16][260];
  __shared__ float Wl[64][65];
  int tid = threadIdx.x;
  int l0 = blockIdx.x*64, b0 = blockIdx.y*16;
  int ll = tid & 63, bq = tid >> 6;
  #pragma unroll
  for (int r=0; r<16; r++) Hs[r][tid] = newhid[(size_t)(b0+r)*D_ + tid];
  float acc[4] = {0.f,0.f,0.f,0.f};
  for (int kt=0; kt<4; kt++){
    int k0 = kt*64;
    __syncthreads();
    #pragma unroll
    for (int r=0; r<4; r++){
      int row = 4*r + bq;
      int l = l0 + row;
      Wl[row][ll] = (l < NLOC) ? W2[(size_t)l*D_ + k0 + ll] : 0.f;
    }
    __syncthreads();
    #pragma unroll
    for (int kk=0; kk<64; kk++){
      float wv = Wl[ll][kk];
      #pragma unroll
      for (int bi=0; bi<4; bi++) acc[bi] += wv * Hs[bq*4+bi][k0+kk];
    }
  }
  int l = l0 + ll;
  if (l < NLOC){
    float bias = b2[l];
    #pragma unroll
    for (int bi=0; bi<4; bi++){
      int b = b0 + bq*4 + bi;
      float mx = mixv[b];
      out[(size_t)b*NLOC + l] = mx*NEGV + (1.0f-mx)*(acc[bi] + bias);
    }
  }
}

// ---- overwrite kept recent locations ----
__global__ void k_scatter(const float* __restrict__ newhid, const float* __restrict__ W2,
                          const float* __restrict__ b2, const float* __restrict__ mixv,
                          const float* __restrict__ scores, const int* __restrict__ rlocs,
                          const int* __restrict__ keep, float* out){
  int b = blockIdx.x, lane = threadIdx.x;
  float mx = mixv[b];
  for (int j=0; j<5; j++){
    if (!keep[b*5+j]) continue;
    int rl = rlocs[b*5+j];
    const float* wr = W2 + (size_t)rl*D_;
    const float* hr = newhid + (size_t)b*D_;
    float a = 0.f;
    #pragma unroll
    for (int q=0; q<4; q++){ int k = lane + 64*q; a += hr[k]*wr[k]; }
    #pragma unroll
    for (int off=32; off>0; off>>=1) a += __shfl_xor(a, off, 64);
    if (lane==0)
      out[(size_t)b*NLOC + rl] = mx*scores[b*5+j] + (1.0f-mx)*(a + b2[rl]);
  }
}

extern "C" void kernel_launch(void* const* d_in, const int* in_sizes, int n_in,
                              void* d_out, int out_size, void* d_ws, size_t ws_size,
                              hipStream_t stream){
  const int* locations   = (const int*)d_in[0];
  const int* users       = (const int*)d_in[1];
  const int* weekdays    = (const int*)d_in[2];
  const int* start_mins  = (const int*)d_in[3];
  const void* mask       = d_in[4];
  const float* loc_table = (const float*)d_in[5];
  const float* user_table= (const float*)d_in[6];
  const float* hour_table= (const float*)d_in[7];
  const float* wd_table  = (const float*)d_in[8];
  const float* W_ih      = (const float*)d_in[9];
  const float* W_hh      = (const float*)d_in[10];
  const float* b_ih      = (const float*)d_in[11];
  const float* b_hh      = (const float*)d_in[12];
  const float* sc_W1     = (const float*)d_in[13];
  const float* sc_b1     = (const float*)d_in[14];
  const float* sc_W2     = (const float*)d_in[15];
  const float* sc_b2     = (const float*)d_in[16];
  const float* np_W1     = (const float*)d_in[17];
  const float* np_b1     = (const float*)d_in[18];
  const float* np_W2     = (const float*)d_in[19];
  const float* np_b2     = (const float*)d_in[20];
  const float* mx_W      = (const float*)d_in[21];
  const float* mx_b      = (const float*)d_in[22];
  float* out = (float*)d_out;

  char* w = (char*)d_ws;
  size_t o = 0;
  auto alloc = [&](size_t bytes)->void*{ void* p = w + o; o += (bytes + 255) & ~(size_t)255; return p; };
  unsigned short* Gx    = (unsigned short*)alloc((size_t)B_*S_*G4*sizeof(short)); // 268 MB bf16, time-major
  unsigned short* Wihbf = (unsigned short*)alloc((size_t)G4*KX*sizeof(short));
  unsigned char*  Ww8   = (unsigned char*)alloc((size_t)G4*D_);                   // fp8 repacked Whh (256 KB)
  float* btot   = (float*)alloc((size_t)G4*sizeof(float));
  float* ctx    = (float*)alloc((size_t)B_*D_*sizeof(float));
  float* newhid = (float*)alloc((size_t)B_*D_*sizeof(float));
  float* mixv   = (float*)alloc((size_t)B_*sizeof(float));
  float* scores = (float*)alloc((size_t)B_*5*sizeof(float));
  int*   slens  = (int*)alloc((size_t)B_*sizeof(int));
  int*   rlocs  = (int*)alloc((size_t)B_*5*sizeof(int));
  int*   keep   = (int*)alloc((size_t)B_*5*sizeof(int));
  int*   flag   = (int*)alloc(sizeof(int));

  k_init<<<1, 64, 0, stream>>>(flag);
  k_detect<<<512, 256, 0, stream>>>((const unsigned char*)mask, flag);
  k_seqlen<<<2, 256, 0, stream>>>(mask, flag, slens);
  k_buildw<<<1792, 256, 0, stream>>>(W_ih, b_ih, b_hh, Wihbf, btot);
  k_packw<<<128, 256, 0, stream>>>(W_hh, Ww8);
  k_gx<<<dim3(8,1024), 256, 0, stream>>>(locations, users, weekdays, start_mins,
                                         loc_table, user_table, hour_table, wd_table,
                                         Wihbf, btot, Gx);
  k_lstm<<<32, 512, 0, stream>>>(Gx, Ww8, ctx, slens);
  k_post1<<<512, 256, 0, stream>>>(ctx, np_W1, np_b1, mx_W, mx_b, newhid, mixv);
  k_recent<<<512, 128, 0, stream>>>(locations, start_mins, slens, loc_table,
                                    sc_W1, sc_b1, sc_W2, sc_b2, scores, rlocs, keep);
  k_final<<<dim3(782,32), 256, 0, stream>>>(newhid, np_W2, np_b2, mixv, out);
  k_scatter<<<512, 64, 0, stream>>>(newhid, np_W2, np_b2, mixv, scores, rlocs, keep, out);
}